// Round 1
// baseline (17027.072 us; speedup 1.0000x reference)
//
#include <hip/hip_runtime.h>
#include <math.h>

#define NB 32768      // batch
#define NH 512        // hidden
#define NM 128        // memory
#define NIN 640       // NH+NM
#define NHID 2048
#define NOUT 642      // NH+NM+2
#define ITERS 16

#define BM 128
#define BN 128
#define BK 8
#define TM 8
#define TN 8
#define NTHREADS 256

// ---------------- init ----------------
__global__ void k_init(float* __restrict__ memb, float* __restrict__ fpb,
                       int* __restrict__ list0, int* __restrict__ cnt) {
  int gid = blockIdx.x * blockDim.x + threadIdx.x;
  if (gid < NB * NM) memb[gid] = ((gid & (NM - 1)) == 0) ? 16.0f : 0.0f;
  if (gid < NB) { fpb[gid] = 0.0f; list0[gid] = gid; }
  if (gid < 32) cnt[gid] = (gid == 0) ? NB : 0;
}

// ---------------- shared microkernel ----------------
__device__ __forceinline__ void mm_tile(const float (*As)[BM + 4], const float (*Bs)[BN + 4],
                                        int ty, int tx, float acc[TM][TN]) {
#pragma unroll
  for (int kk = 0; kk < BK; ++kk) {
    float a[TM], b[TN];
    *(float4*)&a[0] = *(const float4*)&As[kk][ty * TM];
    *(float4*)&a[4] = *(const float4*)&As[kk][ty * TM + 4];
    *(float4*)&b[0] = *(const float4*)&Bs[kk][tx * TN];
    *(float4*)&b[4] = *(const float4*)&Bs[kk][tx * TN + 4];
#pragma unroll
    for (int i = 0; i < TM; ++i)
#pragma unroll
      for (int j = 0; j < TN; ++j)
        acc[i][j] = fmaf(a[i], b[j], acc[i][j]);
  }
}

// ---------------- layer 1: gather concat(x,mem) @ W1, relu+b1 -> h1 ----------------
__global__ __launch_bounds__(NTHREADS) void k_l1(
    const float* __restrict__ xb, const float* __restrict__ memb,
    const float* __restrict__ W1, const float* __restrict__ b1,
    float* __restrict__ h1, const int* __restrict__ list,
    const int* __restrict__ cntp, int chunk_off, int chunk_rows) {
  int cnt = *cntp;
  int lm0 = blockIdx.x * BM;
  int bm0 = chunk_off + lm0;
  if (bm0 >= cnt) return;
  int lim = cnt - chunk_off; if (lim > chunk_rows) lim = chunk_rows;
  int bn0 = blockIdx.y * BN;

  __shared__ float As[BK][BM + 4];
  __shared__ float Bs[BK][BN + 4];

  int tid = threadIdx.x;
  int tx = tid & 15, ty = tid >> 4;

  int am = tid >> 1;
  int ak = (tid & 1) * 4;
  int apg = bm0 + am;
  int aidx = list[apg < cnt ? apg : (cnt - 1)];
  const float* ax = xb + (size_t)aidx * NH;
  const float* amem = memb + (size_t)aidx * NM;

  int bkr = tid >> 5;
  int bn4 = (tid & 31) * 4;
  const float* bsrc = W1 + (size_t)bkr * NHID + bn0 + bn4;

  float acc[TM][TN];
#pragma unroll
  for (int i = 0; i < TM; ++i)
#pragma unroll
    for (int j = 0; j < TN; ++j) acc[i][j] = 0.0f;

  for (int k0 = 0; k0 < NIN; k0 += BK) {
    int k = k0 + ak;
    float4 av;
    if (k < NH) av = *(const float4*)(ax + k);
    else        av = *(const float4*)(amem + (k - NH));
    float4 bv = *(const float4*)(bsrc + (size_t)k0 * NHID);
    As[ak + 0][am] = av.x; As[ak + 1][am] = av.y;
    As[ak + 2][am] = av.z; As[ak + 3][am] = av.w;
    *(float4*)&Bs[bkr][bn4] = bv;
    __syncthreads();
    mm_tile(As, Bs, ty, tx, acc);
    __syncthreads();
  }

#pragma unroll
  for (int i = 0; i < TM; ++i) {
    int lrow = lm0 + ty * TM + i;
    if (lrow >= lim) continue;
#pragma unroll
    for (int j = 0; j < TN; j += 4) {
      int n = bn0 + tx * TN + j;
      float4 o;
      o.x = fmaxf(acc[i][j + 0] + b1[n + 0], 0.0f);
      o.y = fmaxf(acc[i][j + 1] + b1[n + 1], 0.0f);
      o.z = fmaxf(acc[i][j + 2] + b1[n + 2], 0.0f);
      o.w = fmaxf(acc[i][j + 3] + b1[n + 3], 0.0f);
      *(float4*)(h1 + (size_t)lrow * NHID + n) = o;
    }
  }
}

// ---------------- layer 2: h1 @ W2, relu+b2 -> h2 ----------------
__global__ __launch_bounds__(NTHREADS) void k_l2(
    const float* __restrict__ h1, const float* __restrict__ W2, const float* __restrict__ b2,
    float* __restrict__ h2, const int* __restrict__ cntp, int chunk_off, int chunk_rows) {
  int cnt = *cntp;
  int lm0 = blockIdx.x * BM;
  int bm0 = chunk_off + lm0;
  if (bm0 >= cnt) return;
  int lim = cnt - chunk_off; if (lim > chunk_rows) lim = chunk_rows;
  int bn0 = blockIdx.y * BN;

  __shared__ float As[BK][BM + 4];
  __shared__ float Bs[BK][BN + 4];

  int tid = threadIdx.x;
  int tx = tid & 15, ty = tid >> 4;

  int am = tid >> 1;
  int ak = (tid & 1) * 4;
  const float* arow = h1 + (size_t)(lm0 + am) * NHID + ak;

  int bkr = tid >> 5;
  int bn4 = (tid & 31) * 4;
  const float* bsrc = W2 + (size_t)bkr * NHID + bn0 + bn4;

  float acc[TM][TN];
#pragma unroll
  for (int i = 0; i < TM; ++i)
#pragma unroll
    for (int j = 0; j < TN; ++j) acc[i][j] = 0.0f;

  for (int k0 = 0; k0 < NHID; k0 += BK) {
    float4 av = *(const float4*)(arow + k0);
    float4 bv = *(const float4*)(bsrc + (size_t)k0 * NHID);
    As[ak + 0][am] = av.x; As[ak + 1][am] = av.y;
    As[ak + 2][am] = av.z; As[ak + 3][am] = av.w;
    *(float4*)&Bs[bkr][bn4] = bv;
    __syncthreads();
    mm_tile(As, Bs, ty, tx, acc);
    __syncthreads();
  }

#pragma unroll
  for (int i = 0; i < TM; ++i) {
    int lrow = lm0 + ty * TM + i;
    if (lrow >= lim) continue;
#pragma unroll
    for (int j = 0; j < TN; j += 4) {
      int n = bn0 + tx * TN + j;
      float4 o;
      o.x = fmaxf(acc[i][j + 0] + b2[n + 0], 0.0f);
      o.y = fmaxf(acc[i][j + 1] + b2[n + 1], 0.0f);
      o.z = fmaxf(acc[i][j + 2] + b2[n + 2], 0.0f);
      o.w = fmaxf(acc[i][j + 3] + b2[n + 3], 0.0f);
      *(float4*)(h2 + (size_t)lrow * NHID + n) = o;
    }
  }
}

// ---------------- layer 3: h2 @ W3 + b3, scatter into x/mem/probs/hv ----------------
__global__ __launch_bounds__(NTHREADS) void k_l3(
    const float* __restrict__ h2, const float* __restrict__ W3, const float* __restrict__ b3,
    float* __restrict__ xb, float* __restrict__ memb,
    float* __restrict__ probs, float* __restrict__ hv,
    const int* __restrict__ list, const int* __restrict__ cntp,
    int chunk_off, int chunk_rows) {
  int cnt = *cntp;
  int lm0 = blockIdx.x * BM;
  int bm0 = chunk_off + lm0;
  if (bm0 >= cnt) return;
  int lim = cnt - chunk_off; if (lim > chunk_rows) lim = chunk_rows;
  int bn0 = blockIdx.y * BN;

  __shared__ float As[BK][BM + 4];
  __shared__ float Bs[BK][BN + 4];

  int tid = threadIdx.x;
  int tx = tid & 15, ty = tid >> 4;

  int am = tid >> 1;
  int ak = (tid & 1) * 4;
  const float* arow = h2 + (size_t)(lm0 + am) * NHID + ak;

  int bkr = tid >> 5;
  int bn4 = (tid & 31) * 4;

  float acc[TM][TN];
#pragma unroll
  for (int i = 0; i < TM; ++i)
#pragma unroll
    for (int j = 0; j < TN; ++j) acc[i][j] = 0.0f;

  for (int k0 = 0; k0 < NHID; k0 += BK) {
    float4 av = *(const float4*)(arow + k0);
    As[ak + 0][am] = av.x; As[ak + 1][am] = av.y;
    As[ak + 2][am] = av.z; As[ak + 3][am] = av.w;
#pragma unroll
    for (int j = 0; j < 4; ++j) {
      int n = bn0 + bn4 + j;
      Bs[bkr][bn4 + j] = (n < NOUT) ? W3[(size_t)(k0 + bkr) * NOUT + n] : 0.0f;
    }
    __syncthreads();
    mm_tile(As, Bs, ty, tx, acc);
    __syncthreads();
  }

#pragma unroll
  for (int i = 0; i < TM; ++i) {
    int lrow = lm0 + ty * TM + i;
    if (lrow >= lim) continue;
    int r = list[chunk_off + lrow];
#pragma unroll
    for (int j = 0; j < TN; ++j) {
      int n = bn0 + tx * TN + j;
      if (n >= NOUT) continue;
      float v = acc[i][j] + b3[n];
      if (n == 0) probs[r] = v;
      else if (n == 1) hv[r] = v;
      else if (n < 2 + NH) xb[(size_t)r * NH + (n - 2)] = v;
      else memb[(size_t)r * NM + (n - 2 - NH)] = v;
    }
  }
}

// ---------------- halt update + compaction of next active list ----------------
__global__ void k_update(const int* __restrict__ listc, int* __restrict__ listn,
                         const float* __restrict__ hv, const float* __restrict__ probs,
                         float* __restrict__ fpb, const int* __restrict__ cntc,
                         int* __restrict__ cntn) {
  int i = blockIdx.x * blockDim.x + threadIdx.x;
  if (i >= *cntc) return;
  int r = listc[i];
  if (hv[r] > 0.0f) {        // sigmoid(hv) > 0.5  <=>  hv > 0
    fpb[r] = probs[r];
  } else {
    int pos = atomicAdd(cntn, 1);
    listn[pos] = r;
  }
}

// ---------------- final: sigmoid(fp) , n_iters = 0 ----------------
__global__ void k_final(const float* __restrict__ fpb, float* __restrict__ out) {
  int i = blockIdx.x * blockDim.x + threadIdx.x;
  if (i < NB) {
    out[i] = 1.0f / (1.0f + expf(-fpb[i]));
    out[NB + i] = 0.0f;
  }
}

extern "C" void kernel_launch(void* const* d_in, const int* in_sizes, int n_in,
                              void* d_out, int out_size, void* d_ws, size_t ws_size,
                              hipStream_t stream) {
  const float* x  = (const float*)d_in[0];
  const float* W1 = (const float*)d_in[1];
  const float* b1 = (const float*)d_in[2];
  const float* W2 = (const float*)d_in[3];
  const float* b2 = (const float*)d_in[4];
  const float* W3 = (const float*)d_in[5];
  const float* b3 = (const float*)d_in[6];
  float* out = (float*)d_out;

  // workspace layout
  char* p = (char*)d_ws;
  auto alloc = [&](size_t bytes) {
    char* r = p;
    p += (bytes + 255) & ~(size_t)255;
    return r;
  };
  float* xb    = (float*)alloc((size_t)NB * NH * 4);
  float* memb  = (float*)alloc((size_t)NB * NM * 4);
  float* fpb   = (float*)alloc((size_t)NB * 4);
  float* probs = (float*)alloc((size_t)NB * 4);
  float* hvb   = (float*)alloc((size_t)NB * 4);
  int*   list0 = (int*)alloc((size_t)NB * 4);
  int*   list1 = (int*)alloc((size_t)NB * 4);
  int*   cnt   = (int*)alloc(32 * 4);

  size_t used = (size_t)(p - (char*)d_ws);
  size_t remain = (ws_size > used) ? (ws_size - used) : 0;
  long long chl = (long long)(remain / ((size_t)2 * NHID * 4));
  int CH = (int)(chl > NB ? NB : chl);
  CH &= ~127;
  if (CH < 128) CH = 128;   // last-resort floor; assumes ws_size >= ~90MB
  float* h1 = (float*)alloc((size_t)CH * NHID * 4);
  float* h2 = (float*)alloc((size_t)CH * NHID * 4);
  int nchunks = (NB + CH - 1) / CH;

  hipMemcpyAsync(xb, x, (size_t)NB * NH * 4, hipMemcpyDeviceToDevice, stream);
  k_init<<<dim3((NB * NM) / 256), 256, 0, stream>>>(memb, fpb, list0, cnt);

  for (int t = 0; t < ITERS; ++t) {
    const int* lc = (t & 1) ? list1 : list0;
    int* ln       = (t & 1) ? list0 : list1;
    const int* cc = cnt + t;
    int* cn       = cnt + t + 1;
    for (int c = 0; c < nchunks; ++c) {
      int off = c * CH;
      int rows = NB - off; if (rows > CH) rows = CH;
      dim3 g1(CH / BM, NHID / BN);
      k_l1<<<g1, NTHREADS, 0, stream>>>(xb, memb, W1, b1, h1, lc, cc, off, rows);
      k_l2<<<g1, NTHREADS, 0, stream>>>(h1, W2, b2, h2, cc, off, rows);
      dim3 g3(CH / BM, (NOUT + BN - 1) / BN);
      k_l3<<<g3, NTHREADS, 0, stream>>>(h2, W3, b3, xb, memb, probs, hvb, lc, cc, off, rows);
    }
    k_update<<<NB / 256, 256, 0, stream>>>(lc, ln, hvb, probs, fpb, cc, cn);
  }
  k_final<<<NB / 256, 256, 0, stream>>>(fpb, out);
}

// Round 4
// 9198.240 us; speedup vs baseline: 1.8511x; 1.8511x over previous
//
#include <hip/hip_runtime.h>
#include <math.h>

typedef _Float16 f16;
typedef _Float16 f16x8 __attribute__((ext_vector_type(8)));
typedef float f32x4 __attribute__((ext_vector_type(4)));

#define NB 32768
#define NH 512
#define NM 128
#define NIN 640
#define NHID 2048
#define NOUT 642
#define NOUTP 768
#define ITERS 16
// 3-split f16: v = a0 + a1*EPS1 + a2*EPS2,  EPS1=2^-11, EPS2=2^-22
#define S1 2048.0f
#define S2 4194304.0f
#define EPS1 4.8828125e-4f
#define EPS2 2.384185791015625e-7f

__device__ __forceinline__ void gload16(const void* g, void* lds) {
  __builtin_amdgcn_global_load_lds(
      reinterpret_cast<const __attribute__((address_space(1))) unsigned int*>((uintptr_t)g),
      reinterpret_cast<__attribute__((address_space(3))) unsigned int*>((unsigned int)(uintptr_t)lds),
      16, 0, 0);
}

__device__ __forceinline__ f32x4 mfma16(f16x8 a, f16x8 b, f32x4 c) {
  return __builtin_amdgcn_mfma_f32_16x16x32_f16(a, b, c, 0, 0, 0);
}

__device__ __forceinline__ void split3(float v, f16& a0, f16& a1, f16& a2) {
  a0 = (f16)v;
  float r1 = v - (float)a0;
  a1 = (f16)(r1 * S1);
  float r2 = r1 - (float)a1 * EPS1;
  a2 = (f16)(r2 * S2);
}

// ---------------- weight transpose + 3-split: W[K][Nreal] -> WT[n][3K] ----------------
__global__ void k_prepW(const float* __restrict__ W, f16* __restrict__ WT,
                        int K, int Nreal) {
  __shared__ float tile[32][33];
  int k0 = blockIdx.x * 32, n0 = blockIdx.y * 32;
  int tx = threadIdx.x & 31, ty = threadIdx.x >> 5;
#pragma unroll
  for (int r = 0; r < 4; ++r) {
    int kk = ty + 8 * r;
    int n = n0 + tx;
    tile[kk][tx] = (n < Nreal) ? W[(size_t)(k0 + kk) * Nreal + n] : 0.0f;
  }
  __syncthreads();
#pragma unroll
  for (int r = 0; r < 4; ++r) {
    int nl = ty + 8 * r;
    float v = tile[tx][nl];
    f16 a0, a1, a2; split3(v, a0, a1, a2);
    size_t o = (size_t)(n0 + nl) * (3 * K) + k0 + tx;
    WT[o] = a0; WT[o + K] = a1; WT[o + 2 * K] = a2;
  }
}

// ---------------- split x into 3-plane interleaved [row][3][NH] ----------------
__global__ void k_splitX(const float* __restrict__ x, f16* __restrict__ x3) {
  int i = blockIdx.x * 256 + threadIdx.x;
  int row = i >> 9, c = i & 511;
  f16 a0, a1, a2; split3(x[i], a0, a1, a2);
  size_t o = (size_t)row * (3 * NH) + c;
  x3[o] = a0; x3[o + NH] = a1; x3[o + 2 * NH] = a2;
}

// ---------------- init mem3/fp/list/cnt ----------------
__global__ void k_init(f16* __restrict__ mem3, float* __restrict__ fpb,
                       int* __restrict__ list0, int* __restrict__ cnt) {
  int gid = blockIdx.x * blockDim.x + threadIdx.x;
  if (gid < NB * NM) {
    int row = gid >> 7, c = gid & 127;
    size_t o = (size_t)row * (3 * NM) + c;
    mem3[o] = (f16)((c == 0) ? 16.0f : 0.0f);
    mem3[o + NM] = (f16)0.0f;
    mem3[o + 2 * NM] = (f16)0.0f;
  }
  if (gid < NB) { fpb[gid] = 0.0f; list0[gid] = gid; }
  if (gid < 32) cnt[gid] = (gid == 0) ? NB : 0;
}

// ===== GEMM: 128x128 tile, BK=32, 512 thr = 8 waves (2x4), wave tile 64x32, 6-pass 3-split =====
// LDS: 6 planes (A0,A1,A2,B0,B1,B2) of [128 rows][32 k] f16, k-slot XOR-swizzled by bits1-2 of row.

#define GEMM_PREAMBLE()                                                     \
  int tid = threadIdx.x;                                                    \
  int w = tid >> 6, lane = tid & 63;                                        \
  int wr = w >> 2, wc = w & 3;                                              \
  int arow0 = 16 * w + (lane >> 2);                                         \
  int stg = 512 * w + 8 * lane;                                             \
  int ksrc = (((lane & 3) ^ ((lane >> 3) & 3)) << 3);                       \
  int lm = lane & 15, kb = lane >> 4;                                       \
  int kidx = ((kb ^ ((lm >> 1) & 3)) << 3);                                 \
  int afo[4], bfo[2];                                                       \
  _Pragma("unroll") for (int m = 0; m < 4; ++m)                             \
    afo[m] = (wr * 64 + m * 16 + lm) * 32 + kidx;                           \
  _Pragma("unroll") for (int n = 0; n < 2; ++n)                             \
    bfo[n] = (wc * 32 + n * 16 + lm) * 32 + kidx;                           \
  f32x4 acc0[4][2], acc1[4][2], acc2[4][2];                                 \
  _Pragma("unroll") for (int m = 0; m < 4; ++m)                             \
  _Pragma("unroll") for (int n = 0; n < 2; ++n) {                           \
    acc0[m][n] = (f32x4)0.0f; acc1[m][n] = (f32x4)0.0f;                     \
    acc2[m][n] = (f32x4)0.0f;                                               \
  }

#define GEMM_COMPUTE()                                                      \
  __syncthreads();                                                          \
  {                                                                         \
    f16x8 fa0[4], fa1[4], fa2[4], fb0[2], fb1[2], fb2[2];                   \
    _Pragma("unroll") for (int m = 0; m < 4; ++m) {                         \
      fa0[m] = *(const f16x8*)&SB[afo[m]];                                  \
      fa1[m] = *(const f16x8*)&SB[4096 + afo[m]];                           \
      fa2[m] = *(const f16x8*)&SB[8192 + afo[m]];                           \
    }                                                                       \
    _Pragma("unroll") for (int n = 0; n < 2; ++n) {                         \
      fb0[n] = *(const f16x8*)&SB[12288 + bfo[n]];                          \
      fb1[n] = *(const f16x8*)&SB[16384 + bfo[n]];                          \
      fb2[n] = *(const f16x8*)&SB[20480 + bfo[n]];                          \
    }                                                                       \
    _Pragma("unroll") for (int m = 0; m < 4; ++m)                           \
    _Pragma("unroll") for (int n = 0; n < 2; ++n) {                         \
      acc0[m][n] = mfma16(fa0[m], fb0[n], acc0[m][n]);                      \
      acc1[m][n] = mfma16(fa0[m], fb1[n], acc1[m][n]);                      \
      acc1[m][n] = mfma16(fa1[m], fb0[n], acc1[m][n]);                      \
      acc2[m][n] = mfma16(fa1[m], fb1[n], acc2[m][n]);                      \
      acc2[m][n] = mfma16(fa0[m], fb2[n], acc2[m][n]);                      \
      acc2[m][n] = mfma16(fa2[m], fb0[n], acc2[m][n]);                      \
    }                                                                       \
  }                                                                         \
  __syncthreads();

#define COMBINE(m, n, q) (acc0[m][n][q] + EPS1 * acc1[m][n][q] + EPS2 * acc2[m][n][q])

// ---------------- layer 1: gather concat(x,mem) @ W1T, relu+b1 -> h1 (3-split) ----------------
__global__ __launch_bounds__(512) void k_l1(
    const f16* __restrict__ x3, const f16* __restrict__ mem3,
    const f16* __restrict__ WT, const float* __restrict__ b1,
    f16* __restrict__ h1, const int* __restrict__ list,
    const int* __restrict__ cntp, int chunk_off, int chunk_rows) {
  int cnt = *cntp;
  int lm0 = blockIdx.x * 128;
  if (chunk_off + lm0 >= cnt) return;
  int lim = cnt - chunk_off; if (lim > chunk_rows) lim = chunk_rows;
  int n0 = blockIdx.y * 128;

  __shared__ f16 SB[6 * 4096];
  GEMM_PREAMBLE();

  int pu = chunk_off + lm0 + arow0;
  int idx = list[pu < cnt ? pu : (cnt - 1)];
  const f16* pX = x3 + (size_t)idx * (3 * NH) + ksrc;
  const f16* pM = mem3 + (size_t)idx * (3 * NM) + ksrc;
  const f16* pB = WT + (size_t)(n0 + arow0) * (3 * NIN) + ksrc;

  for (int k0 = 0; k0 < NIN; k0 += 32) {
    if (k0 < NH) {
#pragma unroll
      for (int s = 0; s < 3; ++s)
        gload16(pX + s * NH + k0, SB + s * 4096 + stg);
    } else {
      int ko = k0 - NH;
#pragma unroll
      for (int s = 0; s < 3; ++s)
        gload16(pM + s * NM + ko, SB + s * 4096 + stg);
    }
#pragma unroll
    for (int s = 0; s < 3; ++s)
      gload16(pB + s * NIN + k0, SB + (3 + s) * 4096 + stg);
    GEMM_COMPUTE();
  }

#pragma unroll
  for (int n = 0; n < 2; ++n) {
    int col = n0 + wc * 32 + n * 16 + lm;
    float bb = b1[col];
#pragma unroll
    for (int m = 0; m < 4; ++m) {
#pragma unroll
      for (int q = 0; q < 4; ++q) {
        int gr = lm0 + wr * 64 + m * 16 + kb * 4 + q;   // chunk-local row (FIX: + lm0)
        if (gr < lim) {
          float v = fmaxf(COMBINE(m, n, q) + bb, 0.0f);
          f16 a0, a1, a2; split3(v, a0, a1, a2);
          size_t o = (size_t)gr * (3 * NHID) + col;
          h1[o] = a0; h1[o + NHID] = a1; h1[o + 2 * NHID] = a2;
        }
      }
    }
  }
}

// ---------------- layer 2: h1 @ W2T, relu+b2 -> h2 (3-split) ----------------
__global__ __launch_bounds__(512) void k_l2(
    const f16* __restrict__ h1, const f16* __restrict__ WT,
    const float* __restrict__ b2, f16* __restrict__ h2,
    const int* __restrict__ cntp, int chunk_off, int chunk_rows) {
  int cnt = *cntp;
  int lm0 = blockIdx.x * 128;
  if (chunk_off + lm0 >= cnt) return;
  int lim = cnt - chunk_off; if (lim > chunk_rows) lim = chunk_rows;
  int n0 = blockIdx.y * 128;

  __shared__ f16 SB[6 * 4096];
  GEMM_PREAMBLE();

  const f16* pA = h1 + (size_t)(lm0 + arow0) * (3 * NHID) + ksrc;
  const f16* pB = WT + (size_t)(n0 + arow0) * (3 * NHID) + ksrc;

  for (int k0 = 0; k0 < NHID; k0 += 32) {
#pragma unroll
    for (int s = 0; s < 3; ++s) {
      gload16(pA + s * NHID + k0, SB + s * 4096 + stg);
      gload16(pB + s * NHID + k0, SB + (3 + s) * 4096 + stg);
    }
    GEMM_COMPUTE();
  }

#pragma unroll
  for (int n = 0; n < 2; ++n) {
    int col = n0 + wc * 32 + n * 16 + lm;
    float bb = b2[col];
#pragma unroll
    for (int m = 0; m < 4; ++m) {
#pragma unroll
      for (int q = 0; q < 4; ++q) {
        int gr = lm0 + wr * 64 + m * 16 + kb * 4 + q;   // chunk-local row (FIX: + lm0)
        if (gr < lim) {
          float v = fmaxf(COMBINE(m, n, q) + bb, 0.0f);
          f16 a0, a1, a2; split3(v, a0, a1, a2);
          size_t o = (size_t)gr * (3 * NHID) + col;
          h2[o] = a0; h2[o + NHID] = a1; h2[o + 2 * NHID] = a2;
        }
      }
    }
  }
}

// ---------------- layer 3: h2 @ W3T + b3 -> scatter probs/hv/x3/mem3 ----------------
__global__ __launch_bounds__(512) void k_l3(
    const f16* __restrict__ h2, const f16* __restrict__ WT,
    const float* __restrict__ b3,
    f16* __restrict__ x3, f16* __restrict__ mem3,
    float* __restrict__ probs, float* __restrict__ hv,
    const int* __restrict__ list, const int* __restrict__ cntp,
    int chunk_off, int chunk_rows) {
  int cnt = *cntp;
  int lm0 = blockIdx.x * 128;
  if (chunk_off + lm0 >= cnt) return;
  int lim = cnt - chunk_off; if (lim > chunk_rows) lim = chunk_rows;
  int n0 = blockIdx.y * 128;

  __shared__ f16 SB[6 * 4096];
  GEMM_PREAMBLE();

  const f16* pA = h2 + (size_t)(lm0 + arow0) * (3 * NHID) + ksrc;
  const f16* pB = WT + (size_t)(n0 + arow0) * (3 * NHID) + ksrc;

  for (int k0 = 0; k0 < NHID; k0 += 32) {
#pragma unroll
    for (int s = 0; s < 3; ++s) {
      gload16(pA + s * NHID + k0, SB + s * 4096 + stg);
      gload16(pB + s * NHID + k0, SB + (3 + s) * 4096 + stg);
    }
    GEMM_COMPUTE();
  }

  float bb[2]; int colv[2];
#pragma unroll
  for (int n = 0; n < 2; ++n) {
    colv[n] = n0 + wc * 32 + n * 16 + lm;
    bb[n] = (colv[n] < NOUT) ? b3[colv[n]] : 0.0f;
  }
#pragma unroll
  for (int m = 0; m < 4; ++m) {
#pragma unroll
    for (int q = 0; q < 4; ++q) {
      int gr = lm0 + wr * 64 + m * 16 + kb * 4 + q;     // chunk-local row (FIX: + lm0)
      if (gr >= lim) continue;
      int r = list[chunk_off + gr];
#pragma unroll
      for (int n = 0; n < 2; ++n) {
        int col = colv[n];
        if (col >= NOUT) continue;
        float v = COMBINE(m, n, q) + bb[n];
        if (col == 0) {
          probs[r] = v;
        } else if (col == 1) {
          hv[r] = v;
        } else if (col < 2 + NH) {
          f16 a0, a1, a2; split3(v, a0, a1, a2);
          size_t o = (size_t)r * (3 * NH) + (col - 2);
          x3[o] = a0; x3[o + NH] = a1; x3[o + 2 * NH] = a2;
        } else {
          f16 a0, a1, a2; split3(v, a0, a1, a2);
          size_t o = (size_t)r * (3 * NM) + (col - 2 - NH);
          mem3[o] = a0; mem3[o + NM] = a1; mem3[o + 2 * NM] = a2;
        }
      }
    }
  }
}

// ---------------- halt update + compaction ----------------
__global__ void k_update(const int* __restrict__ listc, int* __restrict__ listn,
                         const float* __restrict__ hv, const float* __restrict__ probs,
                         float* __restrict__ fpb, const int* __restrict__ cntc,
                         int* __restrict__ cntn) {
  int i = blockIdx.x * blockDim.x + threadIdx.x;
  if (i >= *cntc) return;
  int r = listc[i];
  if (hv[r] > 0.0f) {
    fpb[r] = probs[r];
  } else {
    int pos = atomicAdd(cntn, 1);
    listn[pos] = r;
  }
}

// ---------------- final ----------------
__global__ void k_final(const float* __restrict__ fpb, float* __restrict__ out) {
  int i = blockIdx.x * blockDim.x + threadIdx.x;
  if (i < NB) {
    out[i] = 1.0f / (1.0f + expf(-fpb[i]));
    out[NB + i] = 0.0f;
  }
}

extern "C" void kernel_launch(void* const* d_in, const int* in_sizes, int n_in,
                              void* d_out, int out_size, void* d_ws, size_t ws_size,
                              hipStream_t stream) {
  const float* x  = (const float*)d_in[0];
  const float* W1 = (const float*)d_in[1];
  const float* b1 = (const float*)d_in[2];
  const float* W2 = (const float*)d_in[3];
  const float* b2 = (const float*)d_in[4];
  const float* W3 = (const float*)d_in[5];
  const float* b3 = (const float*)d_in[6];
  float* out = (float*)d_out;

  char* p = (char*)d_ws;
  auto alloc = [&](size_t bytes) {
    char* r = p;
    p += (bytes + 255) & ~(size_t)255;
    return r;
  };
  f16* x3   = (f16*)alloc((size_t)NB * 3 * NH * 2);      // 96 MiB
  f16* mem3 = (f16*)alloc((size_t)NB * 3 * NM * 2);      // 24 MiB
  f16* W1T  = (f16*)alloc((size_t)NHID * 3 * NIN * 2);   // 7.5 MiB
  f16* W2T  = (f16*)alloc((size_t)NHID * 3 * NHID * 2);  // 24 MiB
  f16* W3T  = (f16*)alloc((size_t)NOUTP * 3 * NHID * 2); // 9 MiB
  float* probs = (float*)alloc((size_t)NB * 4);
  float* hvb   = (float*)alloc((size_t)NB * 4);
  float* fpb   = (float*)alloc((size_t)NB * 4);
  int* list0   = (int*)alloc((size_t)NB * 4);
  int* list1   = (int*)alloc((size_t)NB * 4);
  int* cnt     = (int*)alloc(32 * 4);

  size_t used = (size_t)(p - (char*)d_ws);
  size_t remain = (ws_size > used) ? (ws_size - used) : 0;
  long long chl = (long long)(remain / ((size_t)2 * 3 * NHID * 2)); // h1+h2 bytes/row = 24576
  int CH = (int)(chl > NB ? NB : chl);
  CH &= ~127;
  if (CH < 128) CH = 128;
  f16* h1 = (f16*)alloc((size_t)CH * 3 * NHID * 2);
  f16* h2 = (f16*)alloc((size_t)CH * 3 * NHID * 2);
  int nchunks = (NB + CH - 1) / CH;

  k_prepW<<<dim3(NIN / 32, NHID / 32), 256, 0, stream>>>(W1, W1T, NIN, NHID);
  k_prepW<<<dim3(NHID / 32, NHID / 32), 256, 0, stream>>>(W2, W2T, NHID, NHID);
  k_prepW<<<dim3(NHID / 32, NOUTP / 32), 256, 0, stream>>>(W3, W3T, NHID, NOUT);
  k_splitX<<<(NB * NH) / 256, 256, 0, stream>>>(x, x3);
  k_init<<<(NB * NM) / 256, 256, 0, stream>>>(mem3, fpb, list0, cnt);

  for (int t = 0; t < ITERS; ++t) {
    const int* lc = (t & 1) ? list1 : list0;
    int* ln       = (t & 1) ? list0 : list1;
    const int* cc = cnt + t;
    int* cn       = cnt + t + 1;
    for (int c = 0; c < nchunks; ++c) {
      int off = c * CH;
      int rows = NB - off; if (rows > CH) rows = CH;
      dim3 g1(CH / 128, NHID / 128);
      k_l1<<<g1, 512, 0, stream>>>(x3, mem3, W1T, b1, h1, lc, cc, off, rows);
      k_l2<<<g1, 512, 0, stream>>>(h1, W2T, b2, h2, cc, off, rows);
      dim3 g3(CH / 128, NOUTP / 128);
      k_l3<<<g3, 512, 0, stream>>>(h2, W3T, b3, x3, mem3, probs, hvb, lc, cc, off, rows);
    }
    k_update<<<NB / 256, 256, 0, stream>>>(lc, ln, hvb, probs, fpb, cc, cn);
  }
  k_final<<<NB / 256, 256, 0, stream>>>(fpb, out);
}

// Round 5
// 7731.784 us; speedup vs baseline: 2.2022x; 1.1897x over previous
//
#include <hip/hip_runtime.h>
#include <math.h>

typedef _Float16 f16;
typedef _Float16 f16x8 __attribute__((ext_vector_type(8)));
typedef float f32x4 __attribute__((ext_vector_type(4)));

#define NB 32768
#define NH 512
#define NM 128
#define NIN 640
#define NHID 2048
#define NOUT 642
#define NOUTP 768
#define ITERS 16
// 3-split f16: v = a0 + a1*EPS1 + a2*EPS2,  EPS1=2^-11, EPS2=2^-22
#define S1 2048.0f
#define S2 4194304.0f
#define EPS1 4.8828125e-4f
#define EPS2 2.384185791015625e-7f

__device__ __forceinline__ void gload16(const void* g, void* lds) {
  __builtin_amdgcn_global_load_lds(
      reinterpret_cast<const __attribute__((address_space(1))) unsigned int*>((uintptr_t)g),
      reinterpret_cast<__attribute__((address_space(3))) unsigned int*>((unsigned int)(uintptr_t)lds),
      16, 0, 0);
}

__device__ __forceinline__ f32x4 mfma16(f16x8 a, f16x8 b, f32x4 c) {
  return __builtin_amdgcn_mfma_f32_16x16x32_f16(a, b, c, 0, 0, 0);
}

__device__ __forceinline__ void split3(float v, f16& a0, f16& a1, f16& a2) {
  a0 = (f16)v;
  float r1 = v - (float)a0;
  a1 = (f16)(r1 * S1);
  float r2 = r1 - (float)a1 * EPS1;
  a2 = (f16)(r2 * S2);
}

// ---------------- weight transpose + 3-split: W[K][Nreal] -> WT[n][3][K] ----------------
__global__ void k_prepW(const float* __restrict__ W, f16* __restrict__ WT,
                        int K, int Nreal) {
  __shared__ float tile[32][33];
  int k0 = blockIdx.x * 32, n0 = blockIdx.y * 32;
  int tx = threadIdx.x & 31, ty = threadIdx.x >> 5;
#pragma unroll
  for (int r = 0; r < 4; ++r) {
    int kk = ty + 8 * r;
    int n = n0 + tx;
    tile[kk][tx] = (n < Nreal) ? W[(size_t)(k0 + kk) * Nreal + n] : 0.0f;
  }
  __syncthreads();
#pragma unroll
  for (int r = 0; r < 4; ++r) {
    int nl = ty + 8 * r;
    float v = tile[tx][nl];
    f16 a0, a1, a2; split3(v, a0, a1, a2);
    size_t o = (size_t)(n0 + nl) * (3 * K) + k0 + tx;
    WT[o] = a0; WT[o + K] = a1; WT[o + 2 * K] = a2;
  }
}

// ---------------- split x into merged state xm3[row][3][640] (x cols 0..511) ----------------
__global__ void k_splitX(const float* __restrict__ x, f16* __restrict__ xm3) {
  int i = blockIdx.x * 256 + threadIdx.x;
  int row = i >> 9, c = i & 511;
  f16 a0, a1, a2; split3(x[i], a0, a1, a2);
  size_t o = (size_t)row * (3 * NIN) + c;
  xm3[o] = a0; xm3[o + NIN] = a1; xm3[o + 2 * NIN] = a2;
}

// ---------------- init mem part of xm3 (cols 512..639), fp/list/cnt ----------------
__global__ void k_init(f16* __restrict__ xm3, float* __restrict__ fpb,
                       int* __restrict__ list0, int* __restrict__ cnt) {
  int gid = blockIdx.x * blockDim.x + threadIdx.x;
  if (gid < NB * NM) {
    int row = gid >> 7, c = gid & 127;
    size_t o = (size_t)row * (3 * NIN) + 512 + c;
    xm3[o] = (f16)((c == 0) ? 16.0f : 0.0f);
    xm3[o + NIN] = (f16)0.0f;
    xm3[o + 2 * NIN] = (f16)0.0f;
  }
  if (gid < NB) { fpb[gid] = 0.0f; list0[gid] = gid; }
  if (gid < 32) cnt[gid] = (gid == 0) ? NB : 0;
}

// ===== GEMM: 128x128 tile, BK=32, 512 thr = 8 waves (2x4), wave tile 64x32, 6-pass 3-split =====
// LDS: DOUBLE-buffered 6 planes (A0,A1,A2,B0,B1,B2) of [128 rows][32 k] f16, k-slot XOR-swizzled.
// Pipeline: per K-step, issue STAGE(next->other buf) first, then ds_read+MFMA on cur buf, then ONE
// __syncthreads() (compiler drains vmcnt(0) before s_barrier -> staged buffer ready for next step).

#define GEMM_PREAMBLE()                                                     \
  int tid = threadIdx.x;                                                    \
  int w = tid >> 6, lane = tid & 63;                                        \
  int wr = w >> 2, wc = w & 3;                                              \
  int arow0 = 16 * w + (lane >> 2);                                         \
  int stg = 512 * w + 8 * lane;                                             \
  int ksrc = (((lane & 3) ^ ((lane >> 3) & 3)) << 3);                       \
  int lm = lane & 15, kb = lane >> 4;                                       \
  int kidx = ((kb ^ ((lm >> 1) & 3)) << 3);                                 \
  int afo[4], bfo[2];                                                       \
  _Pragma("unroll") for (int m = 0; m < 4; ++m)                             \
    afo[m] = (wr * 64 + m * 16 + lm) * 32 + kidx;                           \
  _Pragma("unroll") for (int n = 0; n < 2; ++n)                             \
    bfo[n] = (wc * 32 + n * 16 + lm) * 32 + kidx;                           \
  f32x4 acc0[4][2], acc1[4][2], acc2[4][2];                                 \
  _Pragma("unroll") for (int m = 0; m < 4; ++m)                             \
  _Pragma("unroll") for (int n = 0; n < 2; ++n) {                           \
    acc0[m][n] = (f32x4)0.0f; acc1[m][n] = (f32x4)0.0f;                     \
    acc2[m][n] = (f32x4)0.0f;                                               \
  }

#define GEMM_COMPUTE(BASE)                                                  \
  {                                                                         \
    const f16* _sb = (BASE);                                                \
    f16x8 fa0[4], fa1[4], fa2[4], fb0[2], fb1[2], fb2[2];                   \
    _Pragma("unroll") for (int m = 0; m < 4; ++m) {                         \
      fa0[m] = *(const f16x8*)&_sb[afo[m]];                                 \
      fa1[m] = *(const f16x8*)&_sb[4096 + afo[m]];                          \
      fa2[m] = *(const f16x8*)&_sb[8192 + afo[m]];                          \
    }                                                                       \
    _Pragma("unroll") for (int n = 0; n < 2; ++n) {                         \
      fb0[n] = *(const f16x8*)&_sb[12288 + bfo[n]];                         \
      fb1[n] = *(const f16x8*)&_sb[16384 + bfo[n]];                         \
      fb2[n] = *(const f16x8*)&_sb[20480 + bfo[n]];                         \
    }                                                                       \
    __builtin_amdgcn_s_setprio(1);                                          \
    _Pragma("unroll") for (int m = 0; m < 4; ++m)                           \
    _Pragma("unroll") for (int n = 0; n < 2; ++n) {                         \
      acc0[m][n] = mfma16(fa0[m], fb0[n], acc0[m][n]);                      \
      acc1[m][n] = mfma16(fa0[m], fb1[n], acc1[m][n]);                      \
      acc1[m][n] = mfma16(fa1[m], fb0[n], acc1[m][n]);                      \
      acc2[m][n] = mfma16(fa1[m], fb1[n], acc2[m][n]);                      \
      acc2[m][n] = mfma16(fa0[m], fb2[n], acc2[m][n]);                      \
      acc2[m][n] = mfma16(fa2[m], fb0[n], acc2[m][n]);                      \
    }                                                                       \
    __builtin_amdgcn_s_setprio(0);                                          \
  }

// stage one 32-k step: 3 A-planes + 3 B-planes into DST (plane stride 4096 f16)
#define STAGE6(K0, DST, PSTRIDE_A, PSTRIDE_B)                               \
  {                                                                         \
    _Pragma("unroll") for (int s = 0; s < 3; ++s) {                         \
      gload16(pA + s * (PSTRIDE_A) + (K0), (DST) + s * 4096 + stg);         \
      gload16(pB + s * (PSTRIDE_B) + (K0), (DST) + (3 + s) * 4096 + stg);   \
    }                                                                       \
  }

#define GEMM_PIPELOOP(KTOT, PSTRIDE_A, PSTRIDE_B)                           \
  f16* SB0 = &SB[0];                                                        \
  f16* SB1 = &SB[24576];                                                    \
  STAGE6(0, SB0, PSTRIDE_A, PSTRIDE_B);                                     \
  __syncthreads();                                                          \
  {                                                                         \
    int pb = 0;                                                             \
    for (int k0 = 0; k0 < (KTOT); k0 += 32, pb ^= 1) {                      \
      f16* curb = pb ? SB1 : SB0;                                           \
      f16* nxtb = pb ? SB0 : SB1;                                           \
      if (k0 + 32 < (KTOT)) STAGE6(k0 + 32, nxtb, PSTRIDE_A, PSTRIDE_B);    \
      GEMM_COMPUTE(curb);                                                   \
      __syncthreads();                                                      \
    }                                                                       \
  }

#define COMBINE(m, n, q) (acc0[m][n][q] + EPS1 * acc1[m][n][q] + EPS2 * acc2[m][n][q])

// ---------------- layer 1: gather xm3 @ W1T, relu+b1 -> h1 (3-split) ----------------
__global__ __launch_bounds__(512) void k_l1(
    const f16* __restrict__ xm3, const f16* __restrict__ WT,
    const float* __restrict__ b1, f16* __restrict__ h1,
    const int* __restrict__ list, const int* __restrict__ cntp,
    int chunk_off, int chunk_rows) {
  int cnt = *cntp;
  int lm0 = blockIdx.x * 128;
  if (chunk_off + lm0 >= cnt) return;
  int lim = cnt - chunk_off; if (lim > chunk_rows) lim = chunk_rows;
  int n0 = blockIdx.y * 128;

  __shared__ f16 SB[2 * 6 * 4096];
  GEMM_PREAMBLE();

  int pu = chunk_off + lm0 + arow0;
  int idx = list[pu < cnt ? pu : (cnt - 1)];
  const f16* pA = xm3 + (size_t)idx * (3 * NIN) + ksrc;
  const f16* pB = WT + (size_t)(n0 + arow0) * (3 * NIN) + ksrc;

  GEMM_PIPELOOP(NIN, NIN, NIN);

#pragma unroll
  for (int n = 0; n < 2; ++n) {
    int col = n0 + wc * 32 + n * 16 + lm;
    float bb = b1[col];
#pragma unroll
    for (int m = 0; m < 4; ++m) {
#pragma unroll
      for (int q = 0; q < 4; ++q) {
        int gr = lm0 + wr * 64 + m * 16 + kb * 4 + q;   // chunk-local row
        if (gr < lim) {
          float v = fmaxf(COMBINE(m, n, q) + bb, 0.0f);
          f16 a0, a1, a2; split3(v, a0, a1, a2);
          size_t o = (size_t)gr * (3 * NHID) + col;
          h1[o] = a0; h1[o + NHID] = a1; h1[o + 2 * NHID] = a2;
        }
      }
    }
  }
}

// ---------------- layer 2: h1 @ W2T, relu+b2 -> h2 (3-split) ----------------
__global__ __launch_bounds__(512) void k_l2(
    const f16* __restrict__ h1, const f16* __restrict__ WT,
    const float* __restrict__ b2, f16* __restrict__ h2,
    const int* __restrict__ cntp, int chunk_off, int chunk_rows) {
  int cnt = *cntp;
  int lm0 = blockIdx.x * 128;
  if (chunk_off + lm0 >= cnt) return;
  int lim = cnt - chunk_off; if (lim > chunk_rows) lim = chunk_rows;
  int n0 = blockIdx.y * 128;

  __shared__ f16 SB[2 * 6 * 4096];
  GEMM_PREAMBLE();

  const f16* pA = h1 + (size_t)(lm0 + arow0) * (3 * NHID) + ksrc;
  const f16* pB = WT + (size_t)(n0 + arow0) * (3 * NHID) + ksrc;

  GEMM_PIPELOOP(NHID, NHID, NHID);

#pragma unroll
  for (int n = 0; n < 2; ++n) {
    int col = n0 + wc * 32 + n * 16 + lm;
    float bb = b2[col];
#pragma unroll
    for (int m = 0; m < 4; ++m) {
#pragma unroll
      for (int q = 0; q < 4; ++q) {
        int gr = lm0 + wr * 64 + m * 16 + kb * 4 + q;   // chunk-local row
        if (gr < lim) {
          float v = fmaxf(COMBINE(m, n, q) + bb, 0.0f);
          f16 a0, a1, a2; split3(v, a0, a1, a2);
          size_t o = (size_t)gr * (3 * NHID) + col;
          h2[o] = a0; h2[o + NHID] = a1; h2[o + 2 * NHID] = a2;
        }
      }
    }
  }
}

// ---------------- layer 3: h2 @ W3T + b3 -> scatter probs/hv/xm3 ----------------
__global__ __launch_bounds__(512) void k_l3(
    const f16* __restrict__ h2, const f16* __restrict__ WT,
    const float* __restrict__ b3, f16* __restrict__ xm3,
    float* __restrict__ probs, float* __restrict__ hv,
    const int* __restrict__ list, const int* __restrict__ cntp,
    int chunk_off, int chunk_rows) {
  int cnt = *cntp;
  int lm0 = blockIdx.x * 128;
  if (chunk_off + lm0 >= cnt) return;
  int lim = cnt - chunk_off; if (lim > chunk_rows) lim = chunk_rows;
  int n0 = blockIdx.y * 128;

  __shared__ f16 SB[2 * 6 * 4096];
  GEMM_PREAMBLE();

  const f16* pA = h2 + (size_t)(lm0 + arow0) * (3 * NHID) + ksrc;
  const f16* pB = WT + (size_t)(n0 + arow0) * (3 * NHID) + ksrc;

  GEMM_PIPELOOP(NHID, NHID, NHID);

  float bb[2]; int colv[2];
#pragma unroll
  for (int n = 0; n < 2; ++n) {
    colv[n] = n0 + wc * 32 + n * 16 + lm;
    bb[n] = (colv[n] < NOUT) ? b3[colv[n]] : 0.0f;
  }
#pragma unroll
  for (int m = 0; m < 4; ++m) {
#pragma unroll
    for (int q = 0; q < 4; ++q) {
      int gr = lm0 + wr * 64 + m * 16 + kb * 4 + q;     // chunk-local row
      if (gr >= lim) continue;
      int r = list[chunk_off + gr];
#pragma unroll
      for (int n = 0; n < 2; ++n) {
        int col = colv[n];
        if (col >= NOUT) continue;
        float v = COMBINE(m, n, q) + bb[n];
        if (col == 0) {
          probs[r] = v;
        } else if (col == 1) {
          hv[r] = v;
        } else if (col < 2 + NH) {
          f16 a0, a1, a2; split3(v, a0, a1, a2);
          size_t o = (size_t)r * (3 * NIN) + (col - 2);
          xm3[o] = a0; xm3[o + NIN] = a1; xm3[o + 2 * NIN] = a2;
        } else {
          f16 a0, a1, a2; split3(v, a0, a1, a2);
          size_t o = (size_t)r * (3 * NIN) + 512 + (col - 2 - NH);
          xm3[o] = a0; xm3[o + NIN] = a1; xm3[o + 2 * NIN] = a2;
        }
      }
    }
  }
}

// ---------------- halt update + compaction ----------------
__global__ void k_update(const int* __restrict__ listc, int* __restrict__ listn,
                         const float* __restrict__ hv, const float* __restrict__ probs,
                         float* __restrict__ fpb, const int* __restrict__ cntc,
                         int* __restrict__ cntn) {
  int i = blockIdx.x * blockDim.x + threadIdx.x;
  if (i >= *cntc) return;
  int r = listc[i];
  if (hv[r] > 0.0f) {
    fpb[r] = probs[r];
  } else {
    int pos = atomicAdd(cntn, 1);
    listn[pos] = r;
  }
}

// ---------------- final ----------------
__global__ void k_final(const float* __restrict__ fpb, float* __restrict__ out) {
  int i = blockIdx.x * blockDim.x + threadIdx.x;
  if (i < NB) {
    out[i] = 1.0f / (1.0f + expf(-fpb[i]));
    out[NB + i] = 0.0f;
  }
}

extern "C" void kernel_launch(void* const* d_in, const int* in_sizes, int n_in,
                              void* d_out, int out_size, void* d_ws, size_t ws_size,
                              hipStream_t stream) {
  const float* x  = (const float*)d_in[0];
  const float* W1 = (const float*)d_in[1];
  const float* b1 = (const float*)d_in[2];
  const float* W2 = (const float*)d_in[3];
  const float* b2 = (const float*)d_in[4];
  const float* W3 = (const float*)d_in[5];
  const float* b3 = (const float*)d_in[6];
  float* out = (float*)d_out;

  char* p = (char*)d_ws;
  auto alloc = [&](size_t bytes) {
    char* r = p;
    p += (bytes + 255) & ~(size_t)255;
    return r;
  };
  f16* xm3  = (f16*)alloc((size_t)NB * 3 * NIN * 2);     // 120 MiB (x||mem, 3 planes)
  f16* W1T  = (f16*)alloc((size_t)NHID * 3 * NIN * 2);   // 7.5 MiB
  f16* W2T  = (f16*)alloc((size_t)NHID * 3 * NHID * 2);  // 24 MiB
  f16* W3T  = (f16*)alloc((size_t)NOUTP * 3 * NHID * 2); // 9 MiB
  float* probs = (float*)alloc((size_t)NB * 4);
  float* hvb   = (float*)alloc((size_t)NB * 4);
  float* fpb   = (float*)alloc((size_t)NB * 4);
  int* list0   = (int*)alloc((size_t)NB * 4);
  int* list1   = (int*)alloc((size_t)NB * 4);
  int* cnt     = (int*)alloc(32 * 4);

  size_t used = (size_t)(p - (char*)d_ws);
  size_t remain = (ws_size > used) ? (ws_size - used) : 0;
  long long chl = (long long)(remain / ((size_t)2 * 3 * NHID * 2)); // h1+h2 bytes/row = 24576
  int CH = (int)(chl > NB ? NB : chl);
  CH &= ~127;
  if (CH < 128) CH = 128;
  f16* h1 = (f16*)alloc((size_t)CH * 3 * NHID * 2);
  f16* h2 = (f16*)alloc((size_t)CH * 3 * NHID * 2);
  int nchunks = (NB + CH - 1) / CH;

  k_prepW<<<dim3(NIN / 32, NHID / 32), 256, 0, stream>>>(W1, W1T, NIN, NHID);
  k_prepW<<<dim3(NHID / 32, NHID / 32), 256, 0, stream>>>(W2, W2T, NHID, NHID);
  k_prepW<<<dim3(NHID / 32, NOUTP / 32), 256, 0, stream>>>(W3, W3T, NHID, NOUT);
  k_splitX<<<(NB * NH) / 256, 256, 0, stream>>>(x, xm3);
  k_init<<<(NB * NM) / 256, 256, 0, stream>>>(xm3, fpb, list0, cnt);

  for (int t = 0; t < ITERS; ++t) {
    const int* lc = (t & 1) ? list1 : list0;
    int* ln       = (t & 1) ? list0 : list1;
    const int* cc = cnt + t;
    int* cn       = cnt + t + 1;
    for (int c = 0; c < nchunks; ++c) {
      int off = c * CH;
      int rows = NB - off; if (rows > CH) rows = CH;
      dim3 g1(CH / 128, NHID / 128);
      k_l1<<<g1, 512, 0, stream>>>(xm3, W1T, b1, h1, lc, cc, off, rows);
      k_l2<<<g1, 512, 0, stream>>>(h1, W2T, b2, h2, cc, off, rows);
      dim3 g3(CH / 128, NOUTP / 128);
      k_l3<<<g3, 512, 0, stream>>>(h2, W3T, b3, xm3, probs, hvb, lc, cc, off, rows);
    }
    k_update<<<NB / 256, 256, 0, stream>>>(lc, ln, hvb, probs, fpb, cc, cn);
  }
  k_final<<<NB / 256, 256, 0, stream>>>(fpb, out);
}

// Round 6
// 7456.187 us; speedup vs baseline: 2.2836x; 1.0370x over previous
//
#include <hip/hip_runtime.h>
#include <math.h>

typedef _Float16 f16;
typedef _Float16 f16x8 __attribute__((ext_vector_type(8)));
typedef float f32x4 __attribute__((ext_vector_type(4)));

#define NB 32768
#define NH 512
#define NM 128
#define NIN 640
#define NHID 2048
#define NOUT 642
#define NOUTP 768
#define ITERS 16
// 3-split f16: v = a0 + a1*EPS1 + a2*EPS2,  EPS1=2^-11, EPS2=2^-22
#define S1 2048.0f
#define S2 4194304.0f
#define EPS1 4.8828125e-4f
#define EPS2 2.384185791015625e-7f

__device__ __forceinline__ void gload16(const void* g, void* lds) {
  __builtin_amdgcn_global_load_lds(
      reinterpret_cast<const __attribute__((address_space(1))) unsigned int*>((uintptr_t)g),
      reinterpret_cast<__attribute__((address_space(3))) unsigned int*>((unsigned int)(uintptr_t)lds),
      16, 0, 0);
}

__device__ __forceinline__ f32x4 mfma16(f16x8 a, f16x8 b, f32x4 c) {
  return __builtin_amdgcn_mfma_f32_16x16x32_f16(a, b, c, 0, 0, 0);
}

__device__ __forceinline__ void split3(float v, f16& a0, f16& a1, f16& a2) {
  a0 = (f16)v;
  float r1 = v - (float)a0;
  a1 = (f16)(r1 * S1);
  float r2 = r1 - (float)a1 * EPS1;
  a2 = (f16)(r2 * S2);
}

// ---------------- weight transpose + 3-split: W[K][Nreal] -> WT[n][3][K] ----------------
__global__ void k_prepW(const float* __restrict__ W, f16* __restrict__ WT,
                        int K, int Nreal) {
  __shared__ float tile[32][33];
  int k0 = blockIdx.x * 32, n0 = blockIdx.y * 32;
  int tx = threadIdx.x & 31, ty = threadIdx.x >> 5;
#pragma unroll
  for (int r = 0; r < 4; ++r) {
    int kk = ty + 8 * r;
    int n = n0 + tx;
    tile[kk][tx] = (n < Nreal) ? W[(size_t)(k0 + kk) * Nreal + n] : 0.0f;
  }
  __syncthreads();
#pragma unroll
  for (int r = 0; r < 4; ++r) {
    int nl = ty + 8 * r;
    float v = tile[tx][nl];
    f16 a0, a1, a2; split3(v, a0, a1, a2);
    size_t o = (size_t)(n0 + nl) * (3 * K) + k0 + tx;
    WT[o] = a0; WT[o + K] = a1; WT[o + 2 * K] = a2;
  }
}

// ---------------- split x into merged state xm3[row][3][640] (x cols 0..511) ----------------
__global__ void k_splitX(const float* __restrict__ x, f16* __restrict__ xm3) {
  int i = blockIdx.x * 256 + threadIdx.x;
  int row = i >> 9, c = i & 511;
  f16 a0, a1, a2; split3(x[i], a0, a1, a2);
  size_t o = (size_t)row * (3 * NIN) + c;
  xm3[o] = a0; xm3[o + NIN] = a1; xm3[o + 2 * NIN] = a2;
}

// ---------------- init mem part of xm3 (cols 512..639), fp/list/cnt ----------------
__global__ void k_init(f16* __restrict__ xm3, float* __restrict__ fpb,
                       int* __restrict__ list0, int* __restrict__ cnt) {
  int gid = blockIdx.x * blockDim.x + threadIdx.x;
  if (gid < NB * NM) {
    int row = gid >> 7, c = gid & 127;
    size_t o = (size_t)row * (3 * NIN) + 512 + c;
    xm3[o] = (f16)((c == 0) ? 16.0f : 0.0f);
    xm3[o + NIN] = (f16)0.0f;
    xm3[o + 2 * NIN] = (f16)0.0f;
  }
  if (gid < NB) { fpb[gid] = 0.0f; list0[gid] = gid; }
  if (gid < 32) cnt[gid] = (gid == 0) ? NB : 0;
}

// ===== GEMM: 128x128 tile, BK=32, 512 thr = 8 waves (2x4), wave tile 64x32, 6-pass 3-split =====
// LDS: TRIPLE-buffered 6 planes (A0,A1,A2,B0,B1,B2) of [128 rows][32 k] f16, k-slot XOR-swizzled.
// 2-deep pipeline, counted vmcnt(6) per K-step (NEVER 0 in main loop), raw s_barrier.
// Per-thread load discipline: exactly 6 global_load_lds per stage -> vmcnt(6) at iter i
// guarantees stage-i landed while stage-(i+1) stays in flight (T4, m218 pattern).

#define GEMM_PREAMBLE()                                                     \
  int tid = threadIdx.x;                                                    \
  int w = tid >> 6, lane = tid & 63;                                        \
  int wr = w >> 2, wc = w & 3;                                              \
  int arow0 = 16 * w + (lane >> 2);                                         \
  int stg = 512 * w + 8 * lane;                                             \
  int ksrc = (((lane & 3) ^ ((lane >> 3) & 3)) << 3);                       \
  int lm = lane & 15, kb = lane >> 4;                                       \
  int kidx = ((kb ^ ((lm >> 1) & 3)) << 3);                                 \
  int afo[4], bfo[2];                                                       \
  _Pragma("unroll") for (int m = 0; m < 4; ++m)                             \
    afo[m] = (wr * 64 + m * 16 + lm) * 32 + kidx;                           \
  _Pragma("unroll") for (int n = 0; n < 2; ++n)                             \
    bfo[n] = (wc * 32 + n * 16 + lm) * 32 + kidx;                           \
  f32x4 acc0[4][2], acc1[4][2], acc2[4][2];                                 \
  _Pragma("unroll") for (int m = 0; m < 4; ++m)                             \
  _Pragma("unroll") for (int n = 0; n < 2; ++n) {                           \
    acc0[m][n] = (f32x4)0.0f; acc1[m][n] = (f32x4)0.0f;                     \
    acc2[m][n] = (f32x4)0.0f;                                               \
  }

#define GEMM_COMPUTE(BASE)                                                  \
  {                                                                         \
    const f16* _sb = (BASE);                                                \
    f16x8 fa0[4], fa1[4], fa2[4], fb0[2], fb1[2], fb2[2];                   \
    _Pragma("unroll") for (int m = 0; m < 4; ++m) {                         \
      fa0[m] = *(const f16x8*)&_sb[afo[m]];                                 \
      fa1[m] = *(const f16x8*)&_sb[4096 + afo[m]];                          \
      fa2[m] = *(const f16x8*)&_sb[8192 + afo[m]];                          \
    }                                                                       \
    _Pragma("unroll") for (int n = 0; n < 2; ++n) {                         \
      fb0[n] = *(const f16x8*)&_sb[12288 + bfo[n]];                         \
      fb1[n] = *(const f16x8*)&_sb[16384 + bfo[n]];                         \
      fb2[n] = *(const f16x8*)&_sb[20480 + bfo[n]];                         \
    }                                                                       \
    __builtin_amdgcn_s_setprio(1);                                          \
    _Pragma("unroll") for (int m = 0; m < 4; ++m)                           \
    _Pragma("unroll") for (int n = 0; n < 2; ++n) {                         \
      acc0[m][n] = mfma16(fa0[m], fb0[n], acc0[m][n]);                      \
      acc1[m][n] = mfma16(fa0[m], fb1[n], acc1[m][n]);                      \
      acc1[m][n] = mfma16(fa1[m], fb0[n], acc1[m][n]);                      \
      acc2[m][n] = mfma16(fa1[m], fb1[n], acc2[m][n]);                      \
      acc2[m][n] = mfma16(fa0[m], fb2[n], acc2[m][n]);                      \
      acc2[m][n] = mfma16(fa2[m], fb0[n], acc2[m][n]);                      \
    }                                                                       \
    __builtin_amdgcn_s_setprio(0);                                          \
  }

// stage one 32-k step: 3 A-planes + 3 B-planes into DST (plane stride 4096 f16)
#define STAGE6(K0, DST, PSTRIDE_A, PSTRIDE_B)                               \
  {                                                                         \
    _Pragma("unroll") for (int s = 0; s < 3; ++s) {                         \
      gload16(pA + s * (PSTRIDE_A) + (K0), (DST) + s * 4096 + stg);         \
      gload16(pB + s * (PSTRIDE_B) + (K0), (DST) + (3 + s) * 4096 + stg);   \
    }                                                                       \
  }

#define VMW6() asm volatile("s_waitcnt vmcnt(6)" ::: "memory")
#define VMW0() asm volatile("s_waitcnt vmcnt(0)" ::: "memory")

// buffer offsets: 0 / 24576 / 49152 f16 (arithmetic rotation, no indexed array)
#define GEMM_PIPELOOP(KTOT, PSTRIDE_A, PSTRIDE_B)                           \
  STAGE6(0, &SB[0], PSTRIDE_A, PSTRIDE_B);                                  \
  STAGE6(32, &SB[24576], PSTRIDE_A, PSTRIDE_B);                             \
  {                                                                         \
    int cur_off = 0;                                                        \
    for (int k0 = 0; k0 < (KTOT); k0 += 32) {                               \
      if (k0 + 32 < (KTOT)) { VMW6(); } else { VMW0(); }                    \
      __builtin_amdgcn_sched_barrier(0);                                    \
      __builtin_amdgcn_s_barrier();                                         \
      __builtin_amdgcn_sched_barrier(0);                                    \
      int nxt_off = cur_off + 49152; if (nxt_off >= 73728) nxt_off -= 73728;\
      if (k0 + 64 < (KTOT)) { f16* nb = &SB[nxt_off];                       \
        STAGE6(k0 + 64, nb, PSTRIDE_A, PSTRIDE_B); }                        \
      GEMM_COMPUTE(&SB[cur_off]);                                           \
      cur_off += 24576; if (cur_off >= 73728) cur_off -= 73728;             \
    }                                                                       \
  }

#define COMBINE(m, n, q) (acc0[m][n][q] + EPS1 * acc1[m][n][q] + EPS2 * acc2[m][n][q])

// ---------------- layer 1: gather xm3 @ W1T, relu+b1 -> h1 (3-split) ----------------
__global__ __launch_bounds__(512) void k_l1(
    const f16* __restrict__ xm3, const f16* __restrict__ WT,
    const float* __restrict__ b1, f16* __restrict__ h1,
    const int* __restrict__ list, const int* __restrict__ cntp,
    int chunk_off, int chunk_rows) {
  int cnt = *cntp;
  int lm0 = blockIdx.x * 128;
  if (chunk_off + lm0 >= cnt) return;
  int lim = cnt - chunk_off; if (lim > chunk_rows) lim = chunk_rows;
  int n0 = blockIdx.y * 128;

  __shared__ f16 SB[3 * 6 * 4096];
  GEMM_PREAMBLE();

  int pu = chunk_off + lm0 + arow0;
  int idx = list[pu < cnt ? pu : (cnt - 1)];
  const f16* pA = xm3 + (size_t)idx * (3 * NIN) + ksrc;
  const f16* pB = WT + (size_t)(n0 + arow0) * (3 * NIN) + ksrc;

  GEMM_PIPELOOP(NIN, NIN, NIN);

#pragma unroll
  for (int n = 0; n < 2; ++n) {
    int col = n0 + wc * 32 + n * 16 + lm;
    float bb = b1[col];
#pragma unroll
    for (int m = 0; m < 4; ++m) {
#pragma unroll
      for (int q = 0; q < 4; ++q) {
        int gr = lm0 + wr * 64 + m * 16 + kb * 4 + q;   // chunk-local row
        if (gr < lim) {
          float v = fmaxf(COMBINE(m, n, q) + bb, 0.0f);
          f16 a0, a1, a2; split3(v, a0, a1, a2);
          size_t o = (size_t)gr * (3 * NHID) + col;
          h1[o] = a0; h1[o + NHID] = a1; h1[o + 2 * NHID] = a2;
        }
      }
    }
  }
}

// ---------------- layer 2: h1 @ W2T, relu+b2 -> h2 (3-split) ----------------
__global__ __launch_bounds__(512) void k_l2(
    const f16* __restrict__ h1, const f16* __restrict__ WT,
    const float* __restrict__ b2, f16* __restrict__ h2,
    const int* __restrict__ cntp, int chunk_off, int chunk_rows) {
  int cnt = *cntp;
  int lm0 = blockIdx.x * 128;
  if (chunk_off + lm0 >= cnt) return;
  int lim = cnt - chunk_off; if (lim > chunk_rows) lim = chunk_rows;
  int n0 = blockIdx.y * 128;

  __shared__ f16 SB[3 * 6 * 4096];
  GEMM_PREAMBLE();

  const f16* pA = h1 + (size_t)(lm0 + arow0) * (3 * NHID) + ksrc;
  const f16* pB = WT + (size_t)(n0 + arow0) * (3 * NHID) + ksrc;

  GEMM_PIPELOOP(NHID, NHID, NHID);

#pragma unroll
  for (int n = 0; n < 2; ++n) {
    int col = n0 + wc * 32 + n * 16 + lm;
    float bb = b2[col];
#pragma unroll
    for (int m = 0; m < 4; ++m) {
#pragma unroll
      for (int q = 0; q < 4; ++q) {
        int gr = lm0 + wr * 64 + m * 16 + kb * 4 + q;   // chunk-local row
        if (gr < lim) {
          float v = fmaxf(COMBINE(m, n, q) + bb, 0.0f);
          f16 a0, a1, a2; split3(v, a0, a1, a2);
          size_t o = (size_t)gr * (3 * NHID) + col;
          h2[o] = a0; h2[o + NHID] = a1; h2[o + 2 * NHID] = a2;
        }
      }
    }
  }
}

// ---------------- layer 3: h2 @ W3T + b3 -> scatter probs/hv/xm3 ----------------
__global__ __launch_bounds__(512) void k_l3(
    const f16* __restrict__ h2, const f16* __restrict__ WT,
    const float* __restrict__ b3, f16* __restrict__ xm3,
    float* __restrict__ probs, float* __restrict__ hv,
    const int* __restrict__ list, const int* __restrict__ cntp,
    int chunk_off, int chunk_rows) {
  int cnt = *cntp;
  int lm0 = blockIdx.x * 128;
  if (chunk_off + lm0 >= cnt) return;
  int lim = cnt - chunk_off; if (lim > chunk_rows) lim = chunk_rows;
  int n0 = blockIdx.y * 128;

  __shared__ f16 SB[3 * 6 * 4096];
  GEMM_PREAMBLE();

  const f16* pA = h2 + (size_t)(lm0 + arow0) * (3 * NHID) + ksrc;
  const f16* pB = WT + (size_t)(n0 + arow0) * (3 * NHID) + ksrc;

  GEMM_PIPELOOP(NHID, NHID, NHID);

  float bb[2]; int colv[2];
#pragma unroll
  for (int n = 0; n < 2; ++n) {
    colv[n] = n0 + wc * 32 + n * 16 + lm;
    bb[n] = (colv[n] < NOUT) ? b3[colv[n]] : 0.0f;
  }
#pragma unroll
  for (int m = 0; m < 4; ++m) {
#pragma unroll
    for (int q = 0; q < 4; ++q) {
      int gr = lm0 + wr * 64 + m * 16 + kb * 4 + q;     // chunk-local row
      if (gr >= lim) continue;
      int r = list[chunk_off + gr];
#pragma unroll
      for (int n = 0; n < 2; ++n) {
        int col = colv[n];
        if (col >= NOUT) continue;
        float v = COMBINE(m, n, q) + bb[n];
        if (col == 0) {
          probs[r] = v;
        } else if (col == 1) {
          hv[r] = v;
        } else if (col < 2 + NH) {
          f16 a0, a1, a2; split3(v, a0, a1, a2);
          size_t o = (size_t)r * (3 * NIN) + (col - 2);
          xm3[o] = a0; xm3[o + NIN] = a1; xm3[o + 2 * NIN] = a2;
        } else {
          f16 a0, a1, a2; split3(v, a0, a1, a2);
          size_t o = (size_t)r * (3 * NIN) + 512 + (col - 2 - NH);
          xm3[o] = a0; xm3[o + NIN] = a1; xm3[o + 2 * NIN] = a2;
        }
      }
    }
  }
}

// ---------------- halt update + compaction ----------------
__global__ void k_update(const int* __restrict__ listc, int* __restrict__ listn,
                         const float* __restrict__ hv, const float* __restrict__ probs,
                         float* __restrict__ fpb, const int* __restrict__ cntc,
                         int* __restrict__ cntn) {
  int i = blockIdx.x * blockDim.x + threadIdx.x;
  if (i >= *cntc) return;
  int r = listc[i];
  if (hv[r] > 0.0f) {
    fpb[r] = probs[r];
  } else {
    int pos = atomicAdd(cntn, 1);
    listn[pos] = r;
  }
}

// ---------------- final ----------------
__global__ void k_final(const float* __restrict__ fpb, float* __restrict__ out) {
  int i = blockIdx.x * blockDim.x + threadIdx.x;
  if (i < NB) {
    out[i] = 1.0f / (1.0f + expf(-fpb[i]));
    out[NB + i] = 0.0f;
  }
}

extern "C" void kernel_launch(void* const* d_in, const int* in_sizes, int n_in,
                              void* d_out, int out_size, void* d_ws, size_t ws_size,
                              hipStream_t stream) {
  const float* x  = (const float*)d_in[0];
  const float* W1 = (const float*)d_in[1];
  const float* b1 = (const float*)d_in[2];
  const float* W2 = (const float*)d_in[3];
  const float* b2 = (const float*)d_in[4];
  const float* W3 = (const float*)d_in[5];
  const float* b3 = (const float*)d_in[6];
  float* out = (float*)d_out;

  char* p = (char*)d_ws;
  auto alloc = [&](size_t bytes) {
    char* r = p;
    p += (bytes + 255) & ~(size_t)255;
    return r;
  };
  f16* xm3  = (f16*)alloc((size_t)NB * 3 * NIN * 2);     // 120 MiB (x||mem, 3 planes)
  f16* W1T  = (f16*)alloc((size_t)NHID * 3 * NIN * 2);   // 7.5 MiB
  f16* W2T  = (f16*)alloc((size_t)NHID * 3 * NHID * 2);  // 24 MiB
  f16* W3T  = (f16*)alloc((size_t)NOUTP * 3 * NHID * 2); // 9 MiB
  float* probs = (float*)alloc((size_t)NB * 4);
  float* hvb   = (float*)alloc((size_t)NB * 4);
  float* fpb   = (float*)alloc((size_t)NB * 4);
  int* list0   = (int*)alloc((size_t)NB * 4);
  int* list1   = (int*)alloc((size_t)NB * 4);
  int* cnt     = (int*)alloc(32 * 4);

  size_t used = (size_t)(p - (char*)d_ws);
  size_t remain = (ws_size > used) ? (ws_size - used) : 0;
  long long chl = (long long)(remain / ((size_t)2 * 3 * NHID * 2)); // h1+h2 bytes/row = 24576
  int CH = (int)(chl > NB ? NB : chl);
  CH &= ~127;
  if (CH < 128) CH = 128;
  f16* h1 = (f16*)alloc((size_t)CH * 3 * NHID * 2);
  f16* h2 = (f16*)alloc((size_t)CH * 3 * NHID * 2);
  int nchunks = (NB + CH - 1) / CH;

  k_prepW<<<dim3(NIN / 32, NHID / 32), 256, 0, stream>>>(W1, W1T, NIN, NHID);
  k_prepW<<<dim3(NHID / 32, NHID / 32), 256, 0, stream>>>(W2, W2T, NHID, NHID);
  k_prepW<<<dim3(NHID / 32, NOUTP / 32), 256, 0, stream>>>(W3, W3T, NHID, NOUT);
  k_splitX<<<(NB * NH) / 256, 256, 0, stream>>>(x, xm3);
  k_init<<<(NB * NM) / 256, 256, 0, stream>>>(xm3, fpb, list0, cnt);

  for (int t = 0; t < ITERS; ++t) {
    const int* lc = (t & 1) ? list1 : list0;
    int* ln       = (t & 1) ? list0 : list1;
    const int* cc = cnt + t;
    int* cn       = cnt + t + 1;
    for (int c = 0; c < nchunks; ++c) {
      int off = c * CH;
      int rows = NB - off; if (rows > CH) rows = CH;
      dim3 g1(CH / 128, NHID / 128);
      k_l1<<<g1, 512, 0, stream>>>(xm3, W1T, b1, h1, lc, cc, off, rows);
      k_l2<<<g1, 512, 0, stream>>>(h1, W2T, b2, h2, cc, off, rows);
      dim3 g3(CH / 128, NOUTP / 128);
      k_l3<<<g3, 512, 0, stream>>>(h2, W3T, b3, xm3, probs, hvb, lc, cc, off, rows);
    }
    k_update<<<NB / 256, 256, 0, stream>>>(lc, ln, hvb, probs, fpb, cc, cn);
  }
  k_final<<<NB / 256, 256, 0, stream>>>(fpb, out);
}